// Round 8
// baseline (212.457 us; speedup 1.0000x reference)
//
#include <hip/hip_runtime.h>

#define NEGV (-10000000000.0f)

typedef unsigned short u16;
typedef _Float16 __attribute__((ext_vector_type(8))) f16x8;
typedef __attribute__((ext_vector_type(4))) float f32x4;

__device__ __forceinline__ u16 f2fh(float f) {
  _Float16 h = (_Float16)f;
  return __builtin_bit_cast(u16, h);
}

__device__ __forceinline__ void gload16(const u16* g, u16* l) {
  __builtin_amdgcn_global_load_lds(
      (const __attribute__((address_space(1))) void*)g,
      (__attribute__((address_space(3))) void*)l, 16, 0, 0);
}

// ---------------------------------------------------------------------------
// grid barrier (all NB blocks co-resident by capacity: __launch_bounds__(256,2)
// -> >=2 blocks/CU * 256 CUs = 512 slots >= NB). Release/acquire via
// device-scope fences + atomics (cross-XCD safe).
// ---------------------------------------------------------------------------
__device__ __forceinline__ void gridbar(unsigned* bar, unsigned nb) {
  __syncthreads();
  if (threadIdx.x == 0) {
    __threadfence();                                  // release phase writes
    unsigned g = atomicAdd(&bar[1], 0u);              // read generation
    if (atomicAdd(&bar[0], 1u) == nb - 1u) {
      atomicExch(&bar[0], 0u);                        // reset arrive count
      __threadfence();
      atomicAdd(&bar[1], 1u);                         // open next generation
    } else {
      while (atomicAdd(&bar[1], 0u) == g)
        __builtin_amdgcn_s_sleep(2);
    }
    __threadfence();                                  // acquire
  }
  __syncthreads();
}

// ---------------------------------------------------------------------------
// 64x64 fp16 MFMA NT tile, 2-phase pipelined (double-buffered LDS).
// EXPOUT: C = exp(2*(acc+bias))  else  C = acc + bias.
// XOR swizzle on global source + LDS read (both-sides rule).
// ---------------------------------------------------------------------------
template <bool EXPOUT>
__device__ __forceinline__ void gemm_mfma64(
    const u16* __restrict__ A, int lda,
    const u16* __restrict__ B, int ldb,
    float* __restrict__ C, int ldc,
    const float* __restrict__ bias,
    int bm, int bn, int t, u16* sA, u16* sB)   // sA,sB: 2*8*512 u16 each
{
  const int l = t & 63, w = t >> 6;
  const int wr = w >> 1, wc = w & 1;
  f32x4 acc[2][2] = {};

  const int srow = l >> 3;
  const int scol = ((l & 7) ^ srow) << 3;

  auto STAGE = [&](int buf, int k0) {
    u16* dA = sA + buf * 4096;
    u16* dB = sB + buf * 4096;
#pragma unroll
    for (int i = 0; i < 4; i++) {
      int s = w * 4 + i;                      // wave-uniform
      if (s < 8) {
        gload16(A + (size_t)(bm + s * 8 + srow) * lda + k0 + scol, dA + s * 512);
      } else {
        int s2 = s - 8;
        gload16(B + (size_t)(bn + s2 * 8 + srow) * ldb + k0 + scol, dB + s2 * 512);
      }
    }
  };

  STAGE(0, 0);
  __syncthreads();

  int cur = 0;
  for (int k0 = 0; k0 < 512; k0 += 64) {
    if (k0 + 64 < 512) STAGE(cur ^ 1, k0 + 64);
    const u16* rA = sA + cur * 4096;
    const u16* rB = sB + cur * 4096;
#pragma unroll
    for (int ks = 0; ks < 2; ks++) {
      f16x8 af[2], bfr[2];
#pragma unroll
      for (int f = 0; f < 2; f++) {
        int row = wr * 32 + f * 16 + (l & 15);
        int cbA = ((ks * 32 + ((l >> 4) << 3)) << 1) ^ ((row & 7) << 4);
        af[f] = *(const f16x8*)((const char*)rA + row * 128 + cbA);
        int col = wc * 32 + f * 16 + (l & 15);
        int cbB = ((ks * 32 + ((l >> 4) << 3)) << 1) ^ ((col & 7) << 4);
        bfr[f] = *(const f16x8*)((const char*)rB + col * 128 + cbB);
      }
#pragma unroll
      for (int fm = 0; fm < 2; fm++)
#pragma unroll
        for (int fn = 0; fn < 2; fn++)
          acc[fm][fn] = __builtin_amdgcn_mfma_f32_16x16x32_f16(
              af[fm], bfr[fn], acc[fm][fn], 0, 0, 0);
    }
    __syncthreads();
    cur ^= 1;
  }

#pragma unroll
  for (int fm = 0; fm < 2; fm++)
#pragma unroll
    for (int fn = 0; fn < 2; fn++) {
      int cn = bn + wc * 32 + fn * 16 + (l & 15);
      float bv = bias ? bias[cn] : 0.0f;
#pragma unroll
      for (int j = 0; j < 4; j++) {
        int rm = bm + wr * 32 + fm * 16 + (l >> 4) * 4 + j;
        float val = acc[fm][fn][j] + bv;
        C[(size_t)rm * ldc + cn] = EXPOUT ? __expf(val * 2.0f) : val;
      }
    }
}

// ---------------------------------------------------------------------------
// mega kernel: prep -> proj -> score+softmax -> pv, grid-barrier separated.
// grid = 512 blocks x 256 threads.
// ---------------------------------------------------------------------------
__global__ __launch_bounds__(256, 2) void mega(
    const float* __restrict__ query, const float* __restrict__ kv,
    const float* __restrict__ W, const float* __restrict__ bias,
    const float* __restrict__ v,
    const int* __restrict__ qlen_p, const int* __restrict__ klen_p,
    float* __restrict__ out,
    float* __restrict__ qpE, float* __restrict__ kpE,
    u16* __restrict__ kvh, u16* __restrict__ kvhT,
    u16* __restrict__ qh, u16* __restrict__ wh,
    unsigned* __restrict__ bar)
{
  __shared__ __align__(16) unsigned char smem[32768];
  u16* sA = (u16*)smem;
  u16* sB = (u16*)(smem + 16384);
  u16* P = qh;                         // alias: qh dead after proj
  const int id = blockIdx.x;
  const int t  = threadIdx.x;

  // ================= phase 0: prep (576 units over 512 blocks) =============
  for (int u = id; u < 576; u += 512) {
    if (u < 64) {
      int idx = u * 256 + t;           // float4 index: query(131072) ++ W(65536)
#pragma unroll
      for (int it = 0; it < 12; it++, idx += 16384) {
        const float4* src; u16* dst; int j;
        if (idx < 131072) { src = (const float4*)query; j = idx;          dst = qh; }
        else              { src = (const float4*)W;     j = idx - 131072; dst = wh; }
        float4 x = src[j];
        ushort4 o;
        o.x = f2fh(x.x); o.y = f2fh(x.y); o.z = f2fh(x.z); o.w = f2fh(x.w);
        *(ushort4*)&dst[(size_t)j * 4] = o;
      }
    } else {
      float (*sT)[68] = (float (*)[68])smem;   // [64 d][68], 17.4KB
      const int tile = u - 64;          // 0..511
      const int b  = tile >> 6;
      const int kt = (tile >> 3) & 7;
      const int dt = tile & 7;
      const int r  = t >> 2;            // 0..63
      const int c4 = t & 3;

      const float4* src = (const float4*)(kv + ((size_t)b * 512 + kt * 64) * 512 + dt * 64);
      ushort4* dkvh = (ushort4*)(kvh + ((size_t)b * 512 + kt * 64) * 512 + dt * 64);

#pragma unroll
      for (int i = 0; i < 4; i++) {
        int j = c4 * 4 + i;             // f4 col within tile, 0..15
        float4 x = src[(size_t)r * 128 + j];
        ushort4 o;
        o.x = f2fh(x.x); o.y = f2fh(x.y); o.z = f2fh(x.z); o.w = f2fh(x.w);
        dkvh[(size_t)r * 128 + j] = o;
        sT[j * 4 + 0][r] = x.x; sT[j * 4 + 1][r] = x.y;
        sT[j * 4 + 2][r] = x.z; sT[j * 4 + 3][r] = x.w;
      }
      __syncthreads();

      u16* dT = kvhT + ((size_t)b * 512 + dt * 64) * 512 + (size_t)kt * 64;
#pragma unroll
      for (int i = 0; i < 4; i++) {
        int j = c4 * 4 + i;
        float4 x = *(const float4*)&sT[r][j * 4];
        ushort4 o;
        o.x = f2fh(x.x); o.y = f2fh(x.y); o.z = f2fh(x.z); o.w = f2fh(x.w);
        *(ushort4*)&dT[(size_t)r * 512 + j * 4] = o;
      }
      __syncthreads();
    }
  }
  gridbar(bar, 512);

  // ================= phase 1: proj (320 units) =============================
  if (id < 320) {
    if (id < 64) {
      gemm_mfma64<true>(qh, 512, wh, 1024, qpE, 256, bias,
                        (id >> 2) * 64, (id & 3) * 64, t, sA, sB);
    } else {
      int r = id - 64;
      int b = r >> 5, w5 = r & 31;
      gemm_mfma64<true>(wh + 512, 1024, kvh + (size_t)b * 512 * 512, 512,
                        kpE + (size_t)b * 256 * 512, 512, nullptr,
                        (w5 & 3) * 64, (w5 >> 2) * 64, t, sA, sB);
    }
  }
  gridbar(bar, 512);

  // ================= phase 2: score + softmax (512 units, 2 q-rows each) ===
  {
    const int b = id >> 6, q0 = (id & 63) * 2;
    const int qlen = qlen_p[b], klen = klen_p[b];
    const int w = t >> 6, l = t & 63;
    const int k1 = w * 64 + l, k2 = k1 + 256;
    u16* Pb = P + (size_t)(b * 128 + q0) * 512;

    if (q0 >= qlen) {                   // both rows masked -> uniform 1/512
      const u16 uh = f2fh(1.0f / 512.0f);
      Pb[k1] = uh; Pb[k2] = uh;
      Pb[512 + k1] = uh; Pb[512 + k2] = uh;
    } else {
      float* sm   = (float*)smem;
      float* sEq  = sm;                 // [2][256]
      float* sV2  = sm + 512;           // [256]
      float* sRed = sm + 768;           // [4 waves][4]

      sV2[t] = 2.0f * v[t];
      sEq[t]       = qpE[(size_t)(b * 128 + q0) * 256 + t];
      sEq[256 + t] = qpE[(size_t)(b * 128 + q0 + 1) * 256 + t]; // q0+1<128 ok
      __syncthreads();

      const float* kc = kpE + (size_t)b * 256 * 512;
      float s1a = 0.f, s2a = 0.f, s1b = 0.f, s2b = 0.f;

      if (k1 - l < klen) {              // this wave's k1-chunk has active k
        if (256 + w * 64 < klen) {      // k2-chunk active too
#pragma unroll 8
          for (int a = 0; a < 256; a++) {
            float ek1 = kc[(size_t)a * 512 + k1];
            float ek2 = kc[(size_t)a * 512 + k2];
            float vv = sV2[a];
            float eqA = sEq[a], eqB = sEq[256 + a];
            s1a = fmaf(-vv, __builtin_amdgcn_rcpf(fmaf(eqA, ek1, 1.0f)), s1a);
            s2a = fmaf(-vv, __builtin_amdgcn_rcpf(fmaf(eqA, ek2, 1.0f)), s2a);
            s1b = fmaf(-vv, __builtin_amdgcn_rcpf(fmaf(eqB, ek1, 1.0f)), s1b);
            s2b = fmaf(-vv, __builtin_amdgcn_rcpf(fmaf(eqB, ek2, 1.0f)), s2b);
          }
        } else {
#pragma unroll 8
          for (int a = 0; a < 256; a++) {
            float ek1 = kc[(size_t)a * 512 + k1];
            float vv = sV2[a];
            float eqA = sEq[a], eqB = sEq[256 + a];
            s1a = fmaf(-vv, __builtin_amdgcn_rcpf(fmaf(eqA, ek1, 1.0f)), s1a);
            s1b = fmaf(-vv, __builtin_amdgcn_rcpf(fmaf(eqB, ek1, 1.0f)), s1b);
          }
        }
      }

      if (k1 >= klen) { s1a = NEGV; s1b = NEGV; }
      if (k2 >= klen) { s2a = NEGV; s2b = NEGV; }

      float mA = fmaxf(s1a, s2a), mB = fmaxf(s1b, s2b);
#pragma unroll
      for (int off = 32; off > 0; off >>= 1) {
        mA = fmaxf(mA, __shfl_xor(mA, off));
        mB = fmaxf(mB, __shfl_xor(mB, off));
      }
      if (l == 0) { sRed[w * 4 + 0] = mA; sRed[w * 4 + 1] = mB; }
      __syncthreads();
      const float MA = fmaxf(fmaxf(sRed[0], sRed[4]),  fmaxf(sRed[8],  sRed[12]));
      const float MB = fmaxf(fmaxf(sRed[1], sRed[5]),  fmaxf(sRed[9],  sRed[13]));

      float e1a = __expf(s1a - MA), e2a = __expf(s2a - MA);  // masked -> 0
      float e1b = __expf(s1b - MB), e2b = __expf(s2b - MB);
      float suA = e1a + e2a, suB = e1b + e2b;
#pragma unroll
      for (int off = 32; off > 0; off >>= 1) {
        suA += __shfl_xor(suA, off);
        suB += __shfl_xor(suB, off);
      }
      if (l == 0) { sRed[w * 4 + 2] = suA; sRed[w * 4 + 3] = suB; }
      __syncthreads();
      const float SA = (sRed[2] + sRed[6]) + (sRed[10] + sRed[14]);
      const float SB = (sRed[3] + sRed[7]) + (sRed[11] + sRed[15]);
      const float rA = __fdividef(1.0f, SA);
      const float rB = __fdividef(1.0f, SB);

      Pb[k1] = f2fh(e1a * rA);
      Pb[k2] = f2fh(e2a * rA);
      if (q0 + 1 < qlen) {
        Pb[512 + k1] = f2fh(e1b * rB);
        Pb[512 + k2] = f2fh(e2b * rB);
      } else {                          // row q0+1 masked -> uniform
        const u16 uh = f2fh(1.0f / 512.0f);
        Pb[512 + k1] = uh;
        Pb[512 + k2] = uh;
      }
    }
  }
  gridbar(bar, 512);

  // ================= phase 3: pv (128 units) ================================
  if (id < 128) {
    const int b = id >> 4, r = id & 15;
    const int mt = r >> 3, nt = r & 7;
    gemm_mfma64<false>(P + (size_t)b * 128 * 512, 512,
                       kvhT + (size_t)b * 512 * 512, 512,
                       out + (size_t)b * 128 * 512, 512, nullptr,
                       mt * 64, nt * 64, t, sA, sB);
  }
}

// ---------------------------------------------------------------------------
extern "C" void kernel_launch(void* const* d_in, const int* in_sizes, int n_in,
                              void* d_out, int out_size, void* d_ws, size_t ws_size,
                              hipStream_t stream)
{
  const float* query = (const float*)d_in[0];  // [8][128][512]
  const float* kv    = (const float*)d_in[1];  // [8][512][512]
  const float* W     = (const float*)d_in[2];  // [256][1024]
  const float* bbias = (const float*)d_in[3];  // [256]
  const float* v     = (const float*)d_in[4];  // [256]
  const int*   qlen  = (const int*)d_in[5];    // [8]
  const int*   klen  = (const int*)d_in[6];    // [8]
  float* out = (float*)d_out;                  // [8][128][512]

  // workspace (14.5 MB + barrier):
  float* qpE  = (float*)d_ws;                  // 1MB   live: proj -> score
  float* kpE  = qpE + 1024 * 256;              // 4MB   live: proj -> score
  u16*   kvh  = (u16*)(kpE + 8 * 256 * 512);   // 4MB   live: prep -> proj
  u16*   kvhT = kvh + 8 * 512 * 512;           // 4MB   live: prep -> pv
  u16*   qh   = kvhT + 8 * 512 * 512;          // 1MB   live: prep->proj; P alias after
  u16*   wh   = qh + 1024 * 512;               // 0.5MB live: prep -> proj
  unsigned* bar = (unsigned*)(wh + 256 * 1024);

  hipMemsetAsync(bar, 0, 2 * sizeof(unsigned), stream);

  mega<<<dim3(512), 256, 0, stream>>>(
      query, kv, W, bbias, v, qlen, klen, out,
      qpE, kpE, kvh, kvhT, qh, wh, bar);
}

// Round 9
// 44.653 us; speedup vs baseline: 4.7579x; 4.7579x over previous
//
#include <hip/hip_runtime.h>

#define NEGV (-10000000000.0f)

typedef unsigned short u16;
typedef _Float16 __attribute__((ext_vector_type(8))) f16x8;
typedef _Float16 __attribute__((ext_vector_type(4))) f16x4;
typedef __attribute__((ext_vector_type(4))) float f32x4;

__device__ __forceinline__ u16 f2fh(float f) {
  _Float16 h = (_Float16)f;
  return __builtin_bit_cast(u16, h);
}

__device__ __forceinline__ void gload16(const u16* g, u16* l) {
  __builtin_amdgcn_global_load_lds(
      (const __attribute__((address_space(1))) void*)g,
      (__attribute__((address_space(3))) void*)l, 16, 0, 0);
}

__device__ __forceinline__ f16x8 cvt8(float4 x, float4 y) {
  f16x8 o;
  o[0] = (_Float16)x.x; o[1] = (_Float16)x.y;
  o[2] = (_Float16)x.z; o[3] = (_Float16)x.w;
  o[4] = (_Float16)y.x; o[5] = (_Float16)y.y;
  o[6] = (_Float16)y.z; o[7] = (_Float16)y.w;
  return o;
}

// ---------------------------------------------------------------------------
// shared MFMA inner step: 64x64 tile in sA/sB ([row][64 fp16] = 128B rows,
// oct-granular XOR swizzle byte ^= (row&7)<<4), 4 waves (2x2), 2x2 fragments.
// ---------------------------------------------------------------------------
__device__ __forceinline__ void mfma_tile(const u16* sA, const u16* sB,
                                          int l, int wr, int wc,
                                          f32x4 (*acc)[2]) {
#pragma unroll
  for (int ks = 0; ks < 2; ks++) {
    f16x8 af[2], bfr[2];
#pragma unroll
    for (int f = 0; f < 2; f++) {
      int cb = (ks * 32 + ((l >> 4) << 3)) << 1;
      int row = wr * 32 + f * 16 + (l & 15);
      af[f] = *(const f16x8*)((const char*)sA + row * 128 + (cb ^ ((row & 7) << 4)));
      int col = wc * 32 + f * 16 + (l & 15);
      bfr[f] = *(const f16x8*)((const char*)sB + col * 128 + (cb ^ ((col & 7) << 4)));
    }
#pragma unroll
    for (int fm = 0; fm < 2; fm++)
#pragma unroll
      for (int fn = 0; fn < 2; fn++)
        acc[fm][fn] = __builtin_amdgcn_mfma_f32_16x16x32_f16(
            af[fm], bfr[fn], acc[fm][fn], 0, 0, 0);
  }
}

// ---------------------------------------------------------------------------
// proj: f32 inputs, on-the-fly fp16 conversion in staging (reg->cvt->ds_write),
// epilogue writes exp(2*(acc+bias)).
// blocks 0..63: qpE = exp(2(query·Wq^T + b)) [1024][256]
// blocks 64..319: kpE = exp(2(Wk·kv[b]^T))   [b][256 a][512 k]
// ---------------------------------------------------------------------------
__global__ __launch_bounds__(256) void proj_mfma(
    const float* __restrict__ query, const float* __restrict__ kv,
    const float* __restrict__ W, const float* __restrict__ bias,
    float* __restrict__ qpE, float* __restrict__ kpE)
{
  __shared__ __align__(16) u16 sA[8 * 512];   // 64 rows x 64 fp16
  __shared__ __align__(16) u16 sB[8 * 512];
  const int id = blockIdx.x, t = threadIdx.x;

  const float *A, *B; float* C;
  int lda, ldb, ldc, bm, bn;
  const float* bp = nullptr;
  if (id < 64) {
    A = query; lda = 512; B = W; ldb = 1024;
    C = qpE; ldc = 256;
    bm = (id >> 2) * 64; bn = (id & 3) * 64;
    bp = bias;
  } else {
    int r = id - 64;
    int b = r >> 5, w5 = r & 31;
    A = W + 512; lda = 1024;
    B = kv + (size_t)b * 512 * 512; ldb = 512;
    C = kpE + (size_t)b * 256 * 512; ldc = 512;
    bm = (w5 & 3) * 64; bn = (w5 >> 2) * 64;
  }

  const int l = t & 63, w = t >> 6;
  const int wr = w >> 1, wc = w & 1;
  const int r0 = t >> 3, oc = t & 7;                // staging row / k-oct
  const int sw0 = (oc * 16) ^ ((r0 & 7) << 4);      // same for r0+32

  f32x4 acc[2][2] = {};
  float4 a00, a01, a10, a11, b00, b01, b10, b11;

  auto LOAD = [&](int k0) {
    const float* pa0 = A + (size_t)(bm + r0) * lda + k0 + oc * 8;
    const float* pa1 = pa0 + (size_t)32 * lda;
    a00 = *(const float4*)pa0; a01 = *(const float4*)(pa0 + 4);
    a10 = *(const float4*)pa1; a11 = *(const float4*)(pa1 + 4);
    const float* pb0 = B + (size_t)(bn + r0) * ldb + k0 + oc * 8;
    const float* pb1 = pb0 + (size_t)32 * ldb;
    b00 = *(const float4*)pb0; b01 = *(const float4*)(pb0 + 4);
    b10 = *(const float4*)pb1; b11 = *(const float4*)(pb1 + 4);
  };
  auto WRITE = [&]() {
    *(f16x8*)((char*)sA + r0 * 128 + sw0)        = cvt8(a00, a01);
    *(f16x8*)((char*)sA + (r0 + 32) * 128 + sw0) = cvt8(a10, a11);
    *(f16x8*)((char*)sB + r0 * 128 + sw0)        = cvt8(b00, b01);
    *(f16x8*)((char*)sB + (r0 + 32) * 128 + sw0) = cvt8(b10, b11);
  };

  LOAD(0);
  for (int k0 = 0; k0 < 512; k0 += 64) {
    __syncthreads();                    // prev MFMA done, LDS writable
    WRITE();
    if (k0 + 64 < 512) LOAD(k0 + 64);   // overlap next loads with MFMA wait
    __syncthreads();                    // tile visible
    mfma_tile(sA, sB, l, wr, wc, acc);
  }

#pragma unroll
  for (int fm = 0; fm < 2; fm++)
#pragma unroll
    for (int fn = 0; fn < 2; fn++) {
      int cn = bn + wc * 32 + fn * 16 + (l & 15);
      float bv = bp ? bp[cn] : 0.0f;
#pragma unroll
      for (int j = 0; j < 4; j++) {
        int rm = bm + wr * 32 + fm * 16 + (l >> 4) * 4 + j;
        C[(size_t)rm * ldc + cn] = __expf((acc[fm][fn][j] + bv) * 2.0f);
      }
    }
}

// ---------------------------------------------------------------------------
// fused score + softmax. Block = 2 q rows x full 512 k (4 waves), grid (64,8).
// score'[q,k] = -sum_a 2 v_a / (1 + eq[q][a]*ek[a][k]) (softmax-equivalent).
// P fp16: masked q -> uniform 1/512; k>=klen -> exact 0.
// ---------------------------------------------------------------------------
__global__ __launch_bounds__(256) void score_softmax(
    const float* __restrict__ qpE,    // [B*128][256] = exp(2(qp+b))
    const float* __restrict__ kpE,    // [B][256][512] = exp(2kp)
    const float* __restrict__ v,
    const int* __restrict__ qlen_p, const int* __restrict__ klen_p,
    u16* __restrict__ P)              // [B][128][512] fp16
{
  const int b = blockIdx.y, q0 = blockIdx.x * 2, t = threadIdx.x;
  const int qlen = qlen_p[b], klen = klen_p[b];
  const int w = t >> 6, l = t & 63;
  const int k1 = w * 64 + l, k2 = k1 + 256;
  u16* Pb = P + (size_t)(b * 128 + q0) * 512;

  if (q0 >= qlen) {                   // both rows masked -> uniform 1/512
    const u16 uh = f2fh(1.0f / 512.0f);
    Pb[k1] = uh; Pb[k2] = uh;
    Pb[512 + k1] = uh; Pb[512 + k2] = uh;
    return;
  }

  __shared__ float sEq[512];
  __shared__ float sV2[256];
  __shared__ float sRed[16];

  sV2[t] = 2.0f * v[t];
  sEq[t]       = qpE[(size_t)(b * 128 + q0) * 256 + t];
  sEq[256 + t] = qpE[(size_t)(b * 128 + q0 + 1) * 256 + t];
  __syncthreads();

  const float* kc = kpE + (size_t)b * 256 * 512;
  float s1a = 0.f, s2a = 0.f, s1b = 0.f, s2b = 0.f;

  if (w * 64 < klen) {                // k1-chunk active
    if (256 + w * 64 < klen) {        // k2-chunk active too
#pragma unroll 8
      for (int a = 0; a < 256; a++) {
        float ek1 = kc[(size_t)a * 512 + k1];
        float ek2 = kc[(size_t)a * 512 + k2];
        float vv = sV2[a];
        float eqA = sEq[a], eqB = sEq[256 + a];
        s1a = fmaf(-vv, __builtin_amdgcn_rcpf(fmaf(eqA, ek1, 1.0f)), s1a);
        s2a = fmaf(-vv, __builtin_amdgcn_rcpf(fmaf(eqA, ek2, 1.0f)), s2a);
        s1b = fmaf(-vv, __builtin_amdgcn_rcpf(fmaf(eqB, ek1, 1.0f)), s1b);
        s2b = fmaf(-vv, __builtin_amdgcn_rcpf(fmaf(eqB, ek2, 1.0f)), s2b);
      }
    } else {
#pragma unroll 8
      for (int a = 0; a < 256; a++) {
        float ek1 = kc[(size_t)a * 512 + k1];
        float vv = sV2[a];
        float eqA = sEq[a], eqB = sEq[256 + a];
        s1a = fmaf(-vv, __builtin_amdgcn_rcpf(fmaf(eqA, ek1, 1.0f)), s1a);
        s1b = fmaf(-vv, __builtin_amdgcn_rcpf(fmaf(eqB, ek1, 1.0f)), s1b);
      }
    }
  }

  if (k1 >= klen) { s1a = NEGV; s1b = NEGV; }
  if (k2 >= klen) { s2a = NEGV; s2b = NEGV; }

  float mA = fmaxf(s1a, s2a), mB = fmaxf(s1b, s2b);
#pragma unroll
  for (int off = 32; off > 0; off >>= 1) {
    mA = fmaxf(mA, __shfl_xor(mA, off));
    mB = fmaxf(mB, __shfl_xor(mB, off));
  }
  if (l == 0) { sRed[w * 4 + 0] = mA; sRed[w * 4 + 1] = mB; }
  __syncthreads();
  const float MA = fmaxf(fmaxf(sRed[0], sRed[4]), fmaxf(sRed[8],  sRed[12]));
  const float MB = fmaxf(fmaxf(sRed[1], sRed[5]), fmaxf(sRed[9],  sRed[13]));

  float e1a = __expf(s1a - MA), e2a = __expf(s2a - MA);   // masked -> exact 0
  float e1b = __expf(s1b - MB), e2b = __expf(s2b - MB);
  float suA = e1a + e2a, suB = e1b + e2b;
#pragma unroll
  for (int off = 32; off > 0; off >>= 1) {
    suA += __shfl_xor(suA, off);
    suB += __shfl_xor(suB, off);
  }
  if (l == 0) { sRed[w * 4 + 2] = suA; sRed[w * 4 + 3] = suB; }
  __syncthreads();
  const float SA = (sRed[2] + sRed[6]) + (sRed[10] + sRed[14]);
  const float SB = (sRed[3] + sRed[7]) + (sRed[11] + sRed[15]);
  const float rA = __fdividef(1.0f, SA);
  const float rB = __fdividef(1.0f, SB);

  Pb[k1] = f2fh(e1a * rA);
  Pb[k2] = f2fh(e2a * rA);
  if (q0 + 1 < qlen) {
    Pb[512 + k1] = f2fh(e1b * rB);
    Pb[512 + k2] = f2fh(e2b * rB);
  } else {
    const u16 uh = f2fh(1.0f / 512.0f);
    Pb[512 + k1] = uh;
    Pb[512 + k2] = uh;
  }
}

// ---------------------------------------------------------------------------
// pv: out[b] = P[b](fp16) @ kv[b](f32, [k][d]) -- NN gemm; B-tile transposed
// to [d][k] fp16 in LDS during staging (4x4 register transpose).
// A (P) staged via global_load_lds. 128 blocks: b(8) x mt(2) x nt(8).
// ---------------------------------------------------------------------------
__global__ __launch_bounds__(256) void pv_mfma(
    const u16* __restrict__ P, const float* __restrict__ kv,
    float* __restrict__ out)
{
  __shared__ __align__(16) u16 sA[8 * 512];
  __shared__ __align__(16) u16 sB[8 * 512];
  const int id = blockIdx.x, t = threadIdx.x;
  const int b = id >> 4, r = id & 15;
  const int bm = (r >> 3) * 64, bn = (r & 7) * 64;

  const u16* Ab = P + (size_t)b * 128 * 512;
  const float* Bb = kv + (size_t)b * 512 * 512;

  const int l = t & 63, w = t >> 6;
  const int wr = w >> 1, wc = w & 1;
  const int srow = l >> 3, scol = ((l & 7) ^ srow) << 3;

  const int dq = t & 15, kq = t >> 4;     // staging: d-quad, k-quad

  float4 v0, v1, v2, v3;
  auto LOADB = [&](int k0) {
    const float* p = Bb + (size_t)(k0 + kq * 4) * 512 + bn + dq * 4;
    v0 = *(const float4*)p;
    v1 = *(const float4*)(p + 512);
    v2 = *(const float4*)(p + 1024);
    v3 = *(const float4*)(p + 1536);
  };
  auto WRITEB = [&]() {
#define WRB(jj, ee)                                                       \
    { int d = dq * 4 + jj;                                                \
      f16x4 c; c[0] = (_Float16)v0.ee; c[1] = (_Float16)v1.ee;            \
      c[2] = (_Float16)v2.ee; c[3] = (_Float16)v3.ee;                     \
      *(f16x4*)((char*)sB + d * 128 +                                     \
                ((((kq >> 1) * 16) ^ ((d & 7) << 4)) + (kq & 1) * 8)) = c; }
    WRB(0, x) WRB(1, y) WRB(2, z) WRB(3, w)
#undef WRB
  };

  f32x4 acc[2][2] = {};
  LOADB(0);
  for (int k0 = 0; k0 < 512; k0 += 64) {
    __syncthreads();
    WRITEB();
#pragma unroll
    for (int i = 0; i < 2; i++) {
      int s = w * 2 + i;                  // wave-uniform seg
      gload16(Ab + (size_t)(bm + s * 8 + srow) * 512 + k0 + scol, sA + s * 512);
    }
    if (k0 + 64 < 512) LOADB(k0 + 64);
    __syncthreads();
    mfma_tile(sA, sB, l, wr, wc, acc);
  }

  float* Cb = out + (size_t)b * 128 * 512;
#pragma unroll
  for (int fm = 0; fm < 2; fm++)
#pragma unroll
    for (int fn = 0; fn < 2; fn++) {
      int cn = bn + wc * 32 + fn * 16 + (l & 15);
#pragma unroll
      for (int j = 0; j < 4; j++) {
        int rm = bm + wr * 32 + fm * 16 + (l >> 4) * 4 + j;
        Cb[(size_t)rm * 512 + cn] = acc[fm][fn][j];
      }
    }
}

// ---------------------------------------------------------------------------
extern "C" void kernel_launch(void* const* d_in, const int* in_sizes, int n_in,
                              void* d_out, int out_size, void* d_ws, size_t ws_size,
                              hipStream_t stream)
{
  const float* query = (const float*)d_in[0];  // [8][128][512]
  const float* kv    = (const float*)d_in[1];  // [8][512][512]
  const float* W     = (const float*)d_in[2];  // [256][1024]
  const float* bbias = (const float*)d_in[3];  // [256]
  const float* v     = (const float*)d_in[4];  // [256]
  const int*   qlen  = (const int*)d_in[5];    // [8]
  const int*   klen  = (const int*)d_in[6];    // [8]
  float* out = (float*)d_out;                  // [8][128][512]

  float* qpE = (float*)d_ws;                   // 1MB
  float* kpE = qpE + 1024 * 256;               // 4MB
  u16*   P   = (u16*)(kpE + 8 * 256 * 512);    // 1MB

  proj_mfma<<<dim3(320), 256, 0, stream>>>(query, kv, W, bbias, qpE, kpE);

  score_softmax<<<dim3(64, 8), 256, 0, stream>>>(
      qpE, kpE, v, qlen, klen, P);

  pv_mfma<<<dim3(128), 256, 0, stream>>>(P, kv, out);
}